// Round 1
// baseline (603.786 us; speedup 1.0000x reference)
//
#include <hip/hip_runtime.h>

#define NPTS 8192
#define BN   16384          // B * N
#define D    32
#define R2   0.0009f        // float32(0.03**2)
#define SIMT 0.7f
#define RAD  0.03f
#define BLOCK 256
#define PBLOCK 512          // pair kernel: 8 waves/block
#define PWAVES 8
#define JSPLIT 4            // blocks per i-group (j-window quartered)
#define NSLICE (PWAVES * JSPLIT)   // 32 wave-slices per i-group
#define NGRP   (BN / 64)           // 256 i-groups
#define ZBINS 512
#define ZSCALE 1280.0f      // ZBINS / 0.4 (points lie in [0, 0.4))
#define AFIELDS 34          // nbc, cnt, acc[32]

// ---------------------------------------------------------------------------
// histscan: z-histograms + inv-norms + leafcnt; LAST block (ticket) runs the
// 4 prefix-scans wave-parallel with shuffles. Cross-block visibility via
// agent-scope atomics (hist written by atomicAdd; read by atomic loads).
// ---------------------------------------------------------------------------
__global__ __launch_bounds__(BLOCK) void histscan_kernel(
    const float* __restrict__ pts, const float* __restrict__ emb,
    const int* __restrict__ leaf, float* __restrict__ invn,
    int* __restrict__ histA, int* __restrict__ histL,
    int* __restrict__ leafcnt, unsigned* __restrict__ done,
    int* __restrict__ rsA, int* __restrict__ rsL,
    int* __restrict__ curA, int* __restrict__ curL) {
  const int p = blockIdx.x * BLOCK + threadIdx.x;
  const float z = pts[3 * p + 2];
  int bin = (int)(z * ZSCALE); if (bin > ZBINS - 1) bin = ZBINS - 1;
  const int b = p >> 13;
  const int lf = leaf[p] > 0;
  atomicAdd(&histA[b * ZBINS + bin], 1);
  if (lf) atomicAdd(&histL[b * ZBINS + bin], 1);

  const float4* er = (const float4*)(emb + (size_t)p * D);
  float ss = 0.f;
#pragma unroll
  for (int i = 0; i < D / 4; ++i) {
    float4 v = er[i];
    ss += v.x * v.x + v.y * v.y + v.z * v.z + v.w * v.w;
  }
  invn[p] = 1.0f / fmaxf(sqrtf(ss), 1e-8f);

  const unsigned long long m = __ballot(lf);
  if ((threadIdx.x & 63) == 0) atomicAdd(&leafcnt[b], (int)__popcll(m));

  // ---- ticket: last finished block does the scans ----
  __shared__ int islast;
  __threadfence();
  if (threadIdx.x == 0) {
    const unsigned t = __hip_atomic_fetch_add(done, 1u, __ATOMIC_ACQ_REL,
                                              __HIP_MEMORY_SCOPE_AGENT);
    islast = (t == gridDim.x - 1);
  }
  __syncthreads();
  if (!islast) return;

  const int wv = threadIdx.x >> 6;      // wave 0..3: {A:b0, A:b1, L:b0, L:b1}
  const int lane = threadIdx.x & 63;
  const int sb = wv & 1;
  const int* __restrict__ h = (wv < 2) ? histA : histL;
  int* __restrict__ rs = (wv < 2) ? rsA : rsL;
  int* __restrict__ cu = (wv < 2) ? curA : curL;
  int carry = 0;
  for (int c = 0; c < ZBINS / 64; ++c) {
    const int idx = c * 64 + lane;
    const int v = __hip_atomic_load(&h[sb * ZBINS + idx], __ATOMIC_RELAXED,
                                    __HIP_MEMORY_SCOPE_AGENT);
    int incl = v;
#pragma unroll
    for (int off = 1; off < 64; off <<= 1) {
      const int t = __shfl_up(incl, off);
      if (lane >= off) incl += t;
    }
    const int excl = carry + incl - v;
    rs[sb * (ZBINS + 1) + idx] = excl;
    cu[sb * ZBINS + idx] = excl;
    carry += __shfl(incl, 63);
  }
  if (lane == 0) rs[sb * (ZBINS + 1) + ZBINS] = carry;
}

// ---------------------------------------------------------------------------
// scatter: counting-sort by z-bin. All points -> sortedA (+perm); leaf points
// -> compacted j-side arrays (pts4L with folded 0.5*(sq-R2), invL, embL).
// ---------------------------------------------------------------------------
__global__ __launch_bounds__(BLOCK) void scatter_kernel(
    const float* __restrict__ pts, const float* __restrict__ emb,
    const int* __restrict__ leaf, const float* __restrict__ invn,
    int* __restrict__ curA, int* __restrict__ curL,
    float4* __restrict__ sortedA, int* __restrict__ permA,
    float4* __restrict__ pts4L, float* __restrict__ invL,
    float* __restrict__ embL) {
  const int p = blockIdx.x * BLOCK + threadIdx.x;
  const float x = pts[3 * p + 0];
  const float y = pts[3 * p + 1];
  const float z = pts[3 * p + 2];
  const float sq = x * x + y * y + z * z;
  const int lf = leaf[p] > 0;
  const float inv = invn[p];
  int bin = (int)(z * ZSCALE); if (bin > ZBINS - 1) bin = ZBINS - 1;
  const int b = p >> 13;

  const int dst = b * NPTS + atomicAdd(&curA[b * ZBINS + bin], 1);
  sortedA[dst] = make_float4(x, y, z, lf ? inv : -inv);  // leaf in sign bit
  permA[dst] = p;

  if (lf) {
    const int dl = b * NPTS + atomicAdd(&curL[b * ZBINS + bin], 1);
    pts4L[dl] = make_float4(x, y, z, 0.5f * (sq - R2));
    invL[dl] = inv;
    const float4* __restrict__ s4 = (const float4*)(emb + (size_t)p * D);
    float4* __restrict__ d4 = (float4*)(embL + (size_t)dl * D);
#pragma unroll
    for (int k = 0; k < D / 4; ++k) d4[k] = s4[k];
  }
}

// ---------------------------------------------------------------------------
// pair + fused reduce/MLP. R9 change: the old shape (256 blocks x 16 waves =
// 1 block/CU, 4 waves/SIMD) was latency-bound: VALUBusy 13.9%, Occupancy 21%
// of the 32-wave cap — per-hit embL scalar-load chains (~250cy each) with
// only 4 waves/SIMD to hide them, plus a straggler tail on 256 single-shot
// blocks. Now each i-group's leaf-window is split across JSPLIT=4 blocks of
// 8 waves (32 slices/group -> 8192 wave-tasks ~= the chip's full 32-wave/CU
// capacity). The inner loop is unchanged (bounds stay readfirstlane-uniform
// -> scalar j loads, 8-wide double-buffered). Each block reduces its waves
// in LDS, stores a private [34][64] partial slice to accG (plain stores, no
// atomics), and the last-arriving block of the group (agent-scope ticket,
// same pattern as histscan) sums the 4 slices and runs the MLP epilogue.
// ---------------------------------------------------------------------------
__global__ __launch_bounds__(PBLOCK, 8) void pair_kernel(
    const float4* __restrict__ sortedA, const int* __restrict__ permA,
    const float4* __restrict__ pts4L, const float* __restrict__ invL,
    const float* __restrict__ embL, const float* __restrict__ emb,
    const int* __restrict__ rsL, const int* __restrict__ leafcnt,
    const float* __restrict__ W1, const float* __restrict__ b1,
    const float* __restrict__ W2, const float* __restrict__ b2,
    float* __restrict__ accG, int* __restrict__ pairdone,
    float* __restrict__ out) {
  const int bid  = blockIdx.x;
  const int ig   = bid >> 2;              // i-group of 64 (0..255), JSPLIT=4
  const int js   = bid & (JSPLIT - 1);    // which window quarter
  const int b    = ig >> 7;               // 128 i-groups per batch
  const int lane = threadIdx.x & 63;
  const int wv   = threadIdx.x >> 6;      // wave 0..7
  const int sg   = ig * 64 + lane;

  __shared__ __align__(16) float red[AFIELDS][64];
  for (int t = threadIdx.x; t < AFIELDS * 64; t += PBLOCK)
    (&red[0][0])[t] = 0.f;
  __syncthreads();

  const float4 A = sortedA[sg];
  const float inv_i = fabsf(A.w);
  const float mhsq = -0.5f * (A.x * A.x + A.y * A.y + A.z * A.z);
  const int p = permA[sg];

  float4 ei[D / 4];                       // e_i; reused as passthrough in tail
  {
    const float4* __restrict__ e4 = (const float4*)(emb + (size_t)p * D);
#pragma unroll
    for (int k = 0; k < D / 4; ++k) ei[k] = e4[k];
  }

  float zmin = A.z, zmax = A.z;
#pragma unroll
  for (int off = 1; off < 64; off <<= 1) {
    zmin = fminf(zmin, __shfl_xor(zmin, off));
    zmax = fmaxf(zmax, __shfl_xor(zmax, off));
  }
  int klo = (int)((zmin - RAD) * ZSCALE) - 1; if (klo < 0) klo = 0;  // fp slack
  int khi = (int)((zmax + RAD) * ZSCALE) + 1; if (khi > ZBINS - 1) khi = ZBINS - 1;
  klo = __builtin_amdgcn_readfirstlane(klo);
  khi = __builtin_amdgcn_readfirstlane(khi);
  const int jlo = b * NPTS + rsL[b * (ZBINS + 1) + klo];
  const int jhi = b * NPTS + rsL[b * (ZBINS + 1) + khi + 1];
  const int len = jhi - jlo;
  const int s = js * PWAVES + wv;         // wave-slice 0..31 of this group
  int c0 = jlo + (len * s) / NSLICE;
  int c1 = jlo + (len * (s + 1)) / NSLICE;
  c0 = __builtin_amdgcn_readfirstlane(c0);
  c1 = __builtin_amdgcn_readfirstlane(c1);

  float acc[D];
#pragma unroll
  for (int d = 0; d < D; ++d) acc[d] = 0.f;
  float nbc = 0.f, cnt = 0.f;

  auto process = [&](const float4 c, const int jj) {
    const float t = fmaf(A.z, c.z, fmaf(A.y, c.y, fmaf(A.x, c.x, mhsq)));
    if (t > c.w) {                        // d2 < R2; j is leaf by construction
      nbc += 1.0f;
      const float4* __restrict__ ej4 = (const float4*)(embL + (size_t)jj * D);
      float s0 = 0.f, s1 = 0.f, s2 = 0.f, s3 = 0.f;
#pragma unroll
      for (int k = 0; k < D / 4; ++k) {
        const float4 vj = ej4[k];         // uniform jj -> scalar loads
        s0 = fmaf(ei[k].x, vj.x, s0);
        s1 = fmaf(ei[k].y, vj.y, s1);
        s2 = fmaf(ei[k].z, vj.z, s2);
        s3 = fmaf(ei[k].w, vj.w, s3);
      }
      const float sm = ((s0 + s1) + (s2 + s3)) * inv_i * invL[jj];
      if (sm > SIMT) {
        cnt += 1.0f;
#pragma unroll
        for (int k = 0; k < D / 4; ++k) {
          const float4 vj = ej4[k];
          acc[4 * k + 0] += vj.x;
          acc[4 * k + 1] += vj.y;
          acc[4 * k + 2] += vj.z;
          acc[4 * k + 3] += vj.w;
        }
      }
    }
  };

  const int nfull = (c1 - c0) & ~7;
  if (nfull > 0) {
    float4 cur[8], nxt[8];
#pragma unroll
    for (int u = 0; u < 8; ++u) cur[u] = pts4L[c0 + u];
    for (int j = c0; j < c0 + nfull; j += 8) {
      const int jn = (j + 8 < c0 + nfull) ? (j + 8) : c0;  // wrap: in-bounds
#pragma unroll
      for (int u = 0; u < 8; ++u) nxt[u] = pts4L[jn + u];
#pragma unroll
      for (int u = 0; u < 8; ++u) process(cur[u], j + u);
#pragma unroll
      for (int u = 0; u < 8; ++u) cur[u] = nxt[u];
    }
  }
  for (int j = c0 + nfull; j < c1; ++j) process(pts4L[j], j);

  // combine the block's 8 waves in LDS (sparse ds-atomics)
  if (nbc != 0.f) atomicAdd(&red[0][lane], nbc);
  if (cnt != 0.f) {
    atomicAdd(&red[1][lane], cnt);
#pragma unroll
    for (int d = 0; d < D; ++d) atomicAdd(&red[2 + d][lane], acc[d]);
  }
  __syncthreads();

  // ---- private partial slice -> global (plain vectorized stores) ----
  {
    float4* __restrict__ g4 =
        (float4*)(accG + (size_t)bid * (AFIELDS * 64));
    const float4* __restrict__ r4 = (const float4*)(&red[0][0]);
    for (int t = threadIdx.x; t < AFIELDS * 16; t += PBLOCK) g4[t] = r4[t];
  }

  // ---- ticket: last-arriving block of this i-group runs the epilogue ----
  __shared__ int lastp;
  __threadfence();
  __syncthreads();
  if (threadIdx.x == 0) {
    const unsigned t = __hip_atomic_fetch_add(
        (unsigned*)&pairdone[ig], 1u, __ATOMIC_ACQ_REL,
        __HIP_MEMORY_SCOPE_AGENT);
    lastp = (t == JSPLIT - 1);
  }
  __syncthreads();
  if (!lastp) return;

  // ---- fused epilogue: wave 0, one lane per point ----
  if (threadIdx.x < 64) {
    const float* __restrict__ gb =
        accG + (size_t)(ig * JSPLIT) * (AFIELDS * 64);
    float tnbc = 0.f, tcnt = 0.f;
    float macc[D];
#pragma unroll
    for (int d = 0; d < D; ++d) macc[d] = 0.f;
#pragma unroll
    for (int ss = 0; ss < JSPLIT; ++ss) {
      const float* __restrict__ sbp = gb + (size_t)ss * (AFIELDS * 64);
      tnbc += __hip_atomic_load(&sbp[0 * 64 + lane], __ATOMIC_RELAXED,
                                __HIP_MEMORY_SCOPE_AGENT);
      tcnt += __hip_atomic_load(&sbp[1 * 64 + lane], __ATOMIC_RELAXED,
                                __HIP_MEMORY_SCOPE_AGENT);
#pragma unroll
      for (int d = 0; d < D; ++d)
        macc[d] += __hip_atomic_load(&sbp[(2 + d) * 64 + lane],
                                     __ATOMIC_RELAXED,
                                     __HIP_MEMORY_SCOPE_AGENT);
    }
    const float rinv = 1.0f / fmaxf(tcnt, 1.0f);

    float e[D];
#pragma unroll
    for (int k = 0; k < D / 4; ++k) {
      e[4 * k + 0] = ei[k].x; e[4 * k + 1] = ei[k].y;
      e[4 * k + 2] = ei[k].z; e[4 * k + 3] = ei[k].w;
    }

    float h[D];
#pragma unroll
    for (int k = 0; k < D; ++k) h[k] = b1[k];
    for (int d = 0; d < D; ++d) {
      const float c = e[d];
      const float* __restrict__ w = W1 + (size_t)d * D;
#pragma unroll
      for (int k = 0; k < D; ++k) h[k] = fmaf(c, w[k], h[k]);
    }
    for (int d = 0; d < D; ++d) {
      const float c = macc[d] * rinv;     // mean_sim[d]
      const float* __restrict__ w = W1 + (size_t)(D + d) * D;
#pragma unroll
      for (int k = 0; k < D; ++k) h[k] = fmaf(c, w[k], h[k]);
    }
#pragma unroll
    for (int k = 0; k < D; ++k) h[k] = fmaxf(h[k], 0.f);

    float o[D];
#pragma unroll
    for (int m = 0; m < D; ++m) o[m] = b2[m];
    for (int k = 0; k < D; ++k) {
      const float c = h[k];
      const float* __restrict__ w = W2 + (size_t)k * D;
#pragma unroll
      for (int m = 0; m < D; ++m) o[m] = fmaf(c, w[m], o[m]);
    }

    const bool lf = A.w > 0.f;
    const bool cond = lf && (tnbc >= 2.0f) && (tcnt >= 1.0f) && (leafcnt[b] >= 10);

    float4* outr = (float4*)(out + (size_t)p * D);
#pragma unroll
    for (int i = 0; i < D / 4; ++i) {
      float4 v;
      if (cond) { v.x = o[4*i+0]; v.y = o[4*i+1]; v.z = o[4*i+2]; v.w = o[4*i+3]; }
      else      { v = ei[i]; }
      outr[i] = v;
    }
  }
}

// ---------------------------------------------------------------------------
extern "C" void kernel_launch(void* const* d_in, const int* in_sizes, int n_in,
                              void* d_out, int out_size, void* d_ws, size_t ws_size,
                              hipStream_t stream) {
  (void)in_sizes; (void)n_in; (void)out_size; (void)ws_size;
  const float* pts  = (const float*)d_in[0];
  const float* emb  = (const float*)d_in[1];
  const int*   leaf = (const int*)d_in[2];
  const float* W1   = (const float*)d_in[3];
  const float* b1   = (const float*)d_in[4];
  const float* W2   = (const float*)d_in[5];
  const float* b2   = (const float*)d_in[6];
  float* out = (float*)d_out;

  char* ws = (char*)d_ws;
  size_t off = 0;
  auto alloc = [&](size_t bytes) { void* r = ws + off; off = (off + bytes + 15) & ~(size_t)15; return r; };

  float4*   sortedA = (float4*)alloc((size_t)BN * 16);
  int*      permA   = (int*)alloc((size_t)BN * 4);
  float4*   pts4L   = (float4*)alloc((size_t)BN * 16);
  float*    invL    = (float*)alloc((size_t)BN * 4);
  float*    embL    = (float*)alloc((size_t)BN * D * 4);
  float*    invn    = (float*)alloc((size_t)BN * 4);
  float*    accG    = (float*)alloc((size_t)NGRP * JSPLIT * AFIELDS * 64 * 4);
  int*      rsA     = (int*)alloc(2 * (ZBINS + 1) * 4);
  int*      rsL     = (int*)alloc(2 * (ZBINS + 1) * 4);
  int*      curA    = (int*)alloc(2 * ZBINS * 4);
  int*      curL    = (int*)alloc(2 * ZBINS * 4);
  int*      histA   = (int*)alloc(2 * ZBINS * 4);   // histA..pairdone contiguous
  int*      histL   = (int*)alloc(2 * ZBINS * 4);   //   -> single 9.2 KB memset
  int*      leafcnt = (int*)alloc(16);
  unsigned* done    = (unsigned*)alloc(16);
  int*      pairdone= (int*)alloc(NGRP * 4);

  hipMemsetAsync(histA, 0, 2 * (2 * ZBINS * 4) + 32 + NGRP * 4, stream);
  histscan_kernel<<<BN / BLOCK, BLOCK, 0, stream>>>(
      pts, emb, leaf, invn, histA, histL, leafcnt, done, rsA, rsL, curA, curL);
  scatter_kernel<<<BN / BLOCK, BLOCK, 0, stream>>>(
      pts, emb, leaf, invn, curA, curL, sortedA, permA, pts4L, invL, embL);
  pair_kernel<<<NGRP * JSPLIT, PBLOCK, 0, stream>>>(
      sortedA, permA, pts4L, invL, embL, emb, rsL, leafcnt,
      W1, b1, W2, b2, accG, pairdone, out);
}

// Round 2
// 293.642 us; speedup vs baseline: 2.0562x; 2.0562x over previous
//
#include <hip/hip_runtime.h>

#define NPTS 8192
#define BN   16384          // B * N
#define D    32
#define R2   0.0009f        // float32(0.03**2)
#define SIMT 0.7f
#define RAD  0.03f
#define BLOCK 256
#define PBLOCK 1024         // pair kernel: 16 waves/block
#define PWAVES 16
#define JSPLIT 2            // blocks per i-group (j-window halved)
#define NSLICE (PWAVES * JSPLIT)   // 32 wave-slices per i-group
#define NGRP   (BN / 64)           // 256 i-groups
#define ZBINS 512
#define ZSCALE 1280.0f      // ZBINS / 0.4 (points lie in [0, 0.4))
#define AFIELDS 34          // nbc, cnt, acc[32]

// ---------------------------------------------------------------------------
// histscan: z-histograms + inv-norms + leafcnt; LAST block (ticket) runs the
// 4 prefix-scans wave-parallel with shuffles. Cross-block visibility via
// agent-scope atomics (hist written by atomicAdd; read by atomic loads).
// ---------------------------------------------------------------------------
__global__ __launch_bounds__(BLOCK) void histscan_kernel(
    const float* __restrict__ pts, const float* __restrict__ emb,
    const int* __restrict__ leaf, float* __restrict__ invn,
    int* __restrict__ histA, int* __restrict__ histL,
    int* __restrict__ leafcnt, unsigned* __restrict__ done,
    int* __restrict__ rsA, int* __restrict__ rsL,
    int* __restrict__ curA, int* __restrict__ curL) {
  const int p = blockIdx.x * BLOCK + threadIdx.x;
  const float z = pts[3 * p + 2];
  int bin = (int)(z * ZSCALE); if (bin > ZBINS - 1) bin = ZBINS - 1;
  const int b = p >> 13;
  const int lf = leaf[p] > 0;
  atomicAdd(&histA[b * ZBINS + bin], 1);
  if (lf) atomicAdd(&histL[b * ZBINS + bin], 1);

  const float4* er = (const float4*)(emb + (size_t)p * D);
  float ss = 0.f;
#pragma unroll
  for (int i = 0; i < D / 4; ++i) {
    float4 v = er[i];
    ss += v.x * v.x + v.y * v.y + v.z * v.z + v.w * v.w;
  }
  invn[p] = 1.0f / fmaxf(sqrtf(ss), 1e-8f);

  const unsigned long long m = __ballot(lf);
  if ((threadIdx.x & 63) == 0) atomicAdd(&leafcnt[b], (int)__popcll(m));

  // ---- ticket: last finished block does the scans ----
  __shared__ int islast;
  __threadfence();
  if (threadIdx.x == 0) {
    const unsigned t = __hip_atomic_fetch_add(done, 1u, __ATOMIC_ACQ_REL,
                                              __HIP_MEMORY_SCOPE_AGENT);
    islast = (t == gridDim.x - 1);
  }
  __syncthreads();
  if (!islast) return;

  const int wv = threadIdx.x >> 6;      // wave 0..3: {A:b0, A:b1, L:b0, L:b1}
  const int lane = threadIdx.x & 63;
  const int sb = wv & 1;
  const int* __restrict__ h = (wv < 2) ? histA : histL;
  int* __restrict__ rs = (wv < 2) ? rsA : rsL;
  int* __restrict__ cu = (wv < 2) ? curA : curL;
  int carry = 0;
  for (int c = 0; c < ZBINS / 64; ++c) {
    const int idx = c * 64 + lane;
    const int v = __hip_atomic_load(&h[sb * ZBINS + idx], __ATOMIC_RELAXED,
                                    __HIP_MEMORY_SCOPE_AGENT);
    int incl = v;
#pragma unroll
    for (int off = 1; off < 64; off <<= 1) {
      const int t = __shfl_up(incl, off);
      if (lane >= off) incl += t;
    }
    const int excl = carry + incl - v;
    rs[sb * (ZBINS + 1) + idx] = excl;
    cu[sb * ZBINS + idx] = excl;
    carry += __shfl(incl, 63);
  }
  if (lane == 0) rs[sb * (ZBINS + 1) + ZBINS] = carry;
}

// ---------------------------------------------------------------------------
// scatter: counting-sort by z-bin. All points -> sortedA (+perm); leaf points
// -> compacted j-side arrays (pts4L with folded 0.5*(sq-R2), invL, embL).
// ---------------------------------------------------------------------------
__global__ __launch_bounds__(BLOCK) void scatter_kernel(
    const float* __restrict__ pts, const float* __restrict__ emb,
    const int* __restrict__ leaf, const float* __restrict__ invn,
    int* __restrict__ curA, int* __restrict__ curL,
    float4* __restrict__ sortedA, int* __restrict__ permA,
    float4* __restrict__ pts4L, float* __restrict__ invL,
    float* __restrict__ embL) {
  const int p = blockIdx.x * BLOCK + threadIdx.x;
  const float x = pts[3 * p + 0];
  const float y = pts[3 * p + 1];
  const float z = pts[3 * p + 2];
  const float sq = x * x + y * y + z * z;
  const int lf = leaf[p] > 0;
  const float inv = invn[p];
  int bin = (int)(z * ZSCALE); if (bin > ZBINS - 1) bin = ZBINS - 1;
  const int b = p >> 13;

  const int dst = b * NPTS + atomicAdd(&curA[b * ZBINS + bin], 1);
  sortedA[dst] = make_float4(x, y, z, lf ? inv : -inv);  // leaf in sign bit
  permA[dst] = p;

  if (lf) {
    const int dl = b * NPTS + atomicAdd(&curL[b * ZBINS + bin], 1);
    pts4L[dl] = make_float4(x, y, z, 0.5f * (sq - R2));
    invL[dl] = inv;
    const float4* __restrict__ s4 = (const float4*)(emb + (size_t)p * D);
    float4* __restrict__ d4 = (float4*)(embL + (size_t)dl * D);
#pragma unroll
    for (int k = 0; k < D / 4; ++k) d4[k] = s4[k];
  }
}

// ---------------------------------------------------------------------------
// pair + fused reduce/MLP. R10: R9's JSPLIT=4 + __launch_bounds__(512,8)
// regressed 10.5x — the min-waves hint cut the VGPR budget to 32 and the
// compiler spilled acc[32]/ei/cur/nxt to scratch (WRITE_SIZE 2MB->158MB,
// VALUBusy 3.8%). The body needs ~60 VGPRs; 60 already sits in the
// 8-waves/SIMD bracket (<=64), so NO register pressure is needed. Keep the
// proven 1024-thread/60-VGPR codegen and get co-residency purely from the
// grid: JSPLIT=2 -> 512 blocks x 16 waves = 2 blocks/CU = 32 waves/CU
// (vs 1 block/CU = 4 waves/SIMD at 123us). Slice length unchanged (len/32).
// Per-block [34][64] partial -> accG (plain stores); last-arriving block of
// the group (agent-scope ticket) merges JSPLIT slices and runs the MLP.
// ---------------------------------------------------------------------------
__global__ __launch_bounds__(PBLOCK) void pair_kernel(
    const float4* __restrict__ sortedA, const int* __restrict__ permA,
    const float4* __restrict__ pts4L, const float* __restrict__ invL,
    const float* __restrict__ embL, const float* __restrict__ emb,
    const int* __restrict__ rsL, const int* __restrict__ leafcnt,
    const float* __restrict__ W1, const float* __restrict__ b1,
    const float* __restrict__ W2, const float* __restrict__ b2,
    float* __restrict__ accG, int* __restrict__ pairdone,
    float* __restrict__ out) {
  const int bid  = blockIdx.x;
  const int ig   = bid >> 1;              // i-group of 64 (0..255), JSPLIT=2
  const int js   = bid & (JSPLIT - 1);    // which window half
  const int b    = ig >> 7;               // 128 i-groups per batch
  const int lane = threadIdx.x & 63;
  const int wv   = threadIdx.x >> 6;      // wave 0..15
  const int sg   = ig * 64 + lane;

  __shared__ __align__(16) float red[AFIELDS][64];
  for (int t = threadIdx.x; t < AFIELDS * 64; t += PBLOCK)
    (&red[0][0])[t] = 0.f;
  __syncthreads();

  const float4 A = sortedA[sg];
  const float inv_i = fabsf(A.w);
  const float mhsq = -0.5f * (A.x * A.x + A.y * A.y + A.z * A.z);
  const int p = permA[sg];

  float4 ei[D / 4];                       // e_i; reused as passthrough in tail
  {
    const float4* __restrict__ e4 = (const float4*)(emb + (size_t)p * D);
#pragma unroll
    for (int k = 0; k < D / 4; ++k) ei[k] = e4[k];
  }

  float zmin = A.z, zmax = A.z;
#pragma unroll
  for (int off = 1; off < 64; off <<= 1) {
    zmin = fminf(zmin, __shfl_xor(zmin, off));
    zmax = fmaxf(zmax, __shfl_xor(zmax, off));
  }
  int klo = (int)((zmin - RAD) * ZSCALE) - 1; if (klo < 0) klo = 0;  // fp slack
  int khi = (int)((zmax + RAD) * ZSCALE) + 1; if (khi > ZBINS - 1) khi = ZBINS - 1;
  klo = __builtin_amdgcn_readfirstlane(klo);
  khi = __builtin_amdgcn_readfirstlane(khi);
  const int jlo = b * NPTS + rsL[b * (ZBINS + 1) + klo];
  const int jhi = b * NPTS + rsL[b * (ZBINS + 1) + khi + 1];
  const int len = jhi - jlo;
  const int s = js * PWAVES + wv;         // wave-slice 0..31 of this group
  int c0 = jlo + (len * s) / NSLICE;
  int c1 = jlo + (len * (s + 1)) / NSLICE;
  c0 = __builtin_amdgcn_readfirstlane(c0);
  c1 = __builtin_amdgcn_readfirstlane(c1);

  float acc[D];
#pragma unroll
  for (int d = 0; d < D; ++d) acc[d] = 0.f;
  float nbc = 0.f, cnt = 0.f;

  auto process = [&](const float4 c, const int jj) {
    const float t = fmaf(A.z, c.z, fmaf(A.y, c.y, fmaf(A.x, c.x, mhsq)));
    if (t > c.w) {                        // d2 < R2; j is leaf by construction
      nbc += 1.0f;
      const float4* __restrict__ ej4 = (const float4*)(embL + (size_t)jj * D);
      float s0 = 0.f, s1 = 0.f, s2 = 0.f, s3 = 0.f;
#pragma unroll
      for (int k = 0; k < D / 4; ++k) {
        const float4 vj = ej4[k];         // uniform jj -> scalar loads
        s0 = fmaf(ei[k].x, vj.x, s0);
        s1 = fmaf(ei[k].y, vj.y, s1);
        s2 = fmaf(ei[k].z, vj.z, s2);
        s3 = fmaf(ei[k].w, vj.w, s3);
      }
      const float sm = ((s0 + s1) + (s2 + s3)) * inv_i * invL[jj];
      if (sm > SIMT) {
        cnt += 1.0f;
#pragma unroll
        for (int k = 0; k < D / 4; ++k) {
          const float4 vj = ej4[k];
          acc[4 * k + 0] += vj.x;
          acc[4 * k + 1] += vj.y;
          acc[4 * k + 2] += vj.z;
          acc[4 * k + 3] += vj.w;
        }
      }
    }
  };

  const int nfull = (c1 - c0) & ~7;
  if (nfull > 0) {
    float4 cur[8], nxt[8];
#pragma unroll
    for (int u = 0; u < 8; ++u) cur[u] = pts4L[c0 + u];
    for (int j = c0; j < c0 + nfull; j += 8) {
      const int jn = (j + 8 < c0 + nfull) ? (j + 8) : c0;  // wrap: in-bounds
#pragma unroll
      for (int u = 0; u < 8; ++u) nxt[u] = pts4L[jn + u];
#pragma unroll
      for (int u = 0; u < 8; ++u) process(cur[u], j + u);
#pragma unroll
      for (int u = 0; u < 8; ++u) cur[u] = nxt[u];
    }
  }
  for (int j = c0 + nfull; j < c1; ++j) process(pts4L[j], j);

  // combine the block's 16 waves in LDS (sparse ds-atomics)
  if (nbc != 0.f) atomicAdd(&red[0][lane], nbc);
  if (cnt != 0.f) {
    atomicAdd(&red[1][lane], cnt);
#pragma unroll
    for (int d = 0; d < D; ++d) atomicAdd(&red[2 + d][lane], acc[d]);
  }
  __syncthreads();

  // ---- private partial slice -> global (plain vectorized stores) ----
  {
    float4* __restrict__ g4 =
        (float4*)(accG + (size_t)bid * (AFIELDS * 64));
    const float4* __restrict__ r4 = (const float4*)(&red[0][0]);
    for (int t = threadIdx.x; t < AFIELDS * 16; t += PBLOCK) g4[t] = r4[t];
  }

  // ---- ticket: last-arriving block of this i-group runs the epilogue ----
  __shared__ int lastp;
  __threadfence();
  __syncthreads();
  if (threadIdx.x == 0) {
    const unsigned t = __hip_atomic_fetch_add(
        (unsigned*)&pairdone[ig], 1u, __ATOMIC_ACQ_REL,
        __HIP_MEMORY_SCOPE_AGENT);
    lastp = (t == JSPLIT - 1);
  }
  __syncthreads();
  if (!lastp) return;

  // ---- fused epilogue: wave 0, one lane per point ----
  if (threadIdx.x < 64) {
    const float* __restrict__ gb =
        accG + (size_t)(ig * JSPLIT) * (AFIELDS * 64);
    float tnbc = 0.f, tcnt = 0.f;
    float macc[D];
#pragma unroll
    for (int d = 0; d < D; ++d) macc[d] = 0.f;
#pragma unroll
    for (int ss = 0; ss < JSPLIT; ++ss) {
      const float* __restrict__ sbp = gb + (size_t)ss * (AFIELDS * 64);
      tnbc += __hip_atomic_load(&sbp[0 * 64 + lane], __ATOMIC_RELAXED,
                                __HIP_MEMORY_SCOPE_AGENT);
      tcnt += __hip_atomic_load(&sbp[1 * 64 + lane], __ATOMIC_RELAXED,
                                __HIP_MEMORY_SCOPE_AGENT);
#pragma unroll
      for (int d = 0; d < D; ++d)
        macc[d] += __hip_atomic_load(&sbp[(2 + d) * 64 + lane],
                                     __ATOMIC_RELAXED,
                                     __HIP_MEMORY_SCOPE_AGENT);
    }
    const float rinv = 1.0f / fmaxf(tcnt, 1.0f);

    float e[D];
#pragma unroll
    for (int k = 0; k < D / 4; ++k) {
      e[4 * k + 0] = ei[k].x; e[4 * k + 1] = ei[k].y;
      e[4 * k + 2] = ei[k].z; e[4 * k + 3] = ei[k].w;
    }

    float h[D];
#pragma unroll
    for (int k = 0; k < D; ++k) h[k] = b1[k];
    for (int d = 0; d < D; ++d) {
      const float c = e[d];
      const float* __restrict__ w = W1 + (size_t)d * D;
#pragma unroll
      for (int k = 0; k < D; ++k) h[k] = fmaf(c, w[k], h[k]);
    }
    for (int d = 0; d < D; ++d) {
      const float c = macc[d] * rinv;     // mean_sim[d]
      const float* __restrict__ w = W1 + (size_t)(D + d) * D;
#pragma unroll
      for (int k = 0; k < D; ++k) h[k] = fmaf(c, w[k], h[k]);
    }
#pragma unroll
    for (int k = 0; k < D; ++k) h[k] = fmaxf(h[k], 0.f);

    float o[D];
#pragma unroll
    for (int m = 0; m < D; ++m) o[m] = b2[m];
    for (int k = 0; k < D; ++k) {
      const float c = h[k];
      const float* __restrict__ w = W2 + (size_t)k * D;
#pragma unroll
      for (int m = 0; m < D; ++m) o[m] = fmaf(c, w[m], o[m]);
    }

    const bool lf = A.w > 0.f;
    const bool cond = lf && (tnbc >= 2.0f) && (tcnt >= 1.0f) && (leafcnt[b] >= 10);

    float4* outr = (float4*)(out + (size_t)p * D);
#pragma unroll
    for (int i = 0; i < D / 4; ++i) {
      float4 v;
      if (cond) { v.x = o[4*i+0]; v.y = o[4*i+1]; v.z = o[4*i+2]; v.w = o[4*i+3]; }
      else      { v = ei[i]; }
      outr[i] = v;
    }
  }
}

// ---------------------------------------------------------------------------
extern "C" void kernel_launch(void* const* d_in, const int* in_sizes, int n_in,
                              void* d_out, int out_size, void* d_ws, size_t ws_size,
                              hipStream_t stream) {
  (void)in_sizes; (void)n_in; (void)out_size; (void)ws_size;
  const float* pts  = (const float*)d_in[0];
  const float* emb  = (const float*)d_in[1];
  const int*   leaf = (const int*)d_in[2];
  const float* W1   = (const float*)d_in[3];
  const float* b1   = (const float*)d_in[4];
  const float* W2   = (const float*)d_in[5];
  const float* b2   = (const float*)d_in[6];
  float* out = (float*)d_out;

  char* ws = (char*)d_ws;
  size_t off = 0;
  auto alloc = [&](size_t bytes) { void* r = ws + off; off = (off + bytes + 15) & ~(size_t)15; return r; };

  float4*   sortedA = (float4*)alloc((size_t)BN * 16);
  int*      permA   = (int*)alloc((size_t)BN * 4);
  float4*   pts4L   = (float4*)alloc((size_t)BN * 16);
  float*    invL    = (float*)alloc((size_t)BN * 4);
  float*    embL    = (float*)alloc((size_t)BN * D * 4);
  float*    invn    = (float*)alloc((size_t)BN * 4);
  float*    accG    = (float*)alloc((size_t)NGRP * JSPLIT * AFIELDS * 64 * 4);
  int*      rsA     = (int*)alloc(2 * (ZBINS + 1) * 4);
  int*      rsL     = (int*)alloc(2 * (ZBINS + 1) * 4);
  int*      curA    = (int*)alloc(2 * ZBINS * 4);
  int*      curL    = (int*)alloc(2 * ZBINS * 4);
  int*      histA   = (int*)alloc(2 * ZBINS * 4);   // histA..pairdone contiguous
  int*      histL   = (int*)alloc(2 * ZBINS * 4);   //   -> single 9.2 KB memset
  int*      leafcnt = (int*)alloc(16);
  unsigned* done    = (unsigned*)alloc(16);
  int*      pairdone= (int*)alloc(NGRP * 4);

  hipMemsetAsync(histA, 0, 2 * (2 * ZBINS * 4) + 32 + NGRP * 4, stream);
  histscan_kernel<<<BN / BLOCK, BLOCK, 0, stream>>>(
      pts, emb, leaf, invn, histA, histL, leafcnt, done, rsA, rsL, curA, curL);
  scatter_kernel<<<BN / BLOCK, BLOCK, 0, stream>>>(
      pts, emb, leaf, invn, curA, curL, sortedA, permA, pts4L, invL, embL);
  pair_kernel<<<NGRP * JSPLIT, PBLOCK, 0, stream>>>(
      sortedA, permA, pts4L, invL, embL, emb, rsL, leafcnt,
      W1, b1, W2, b2, accG, pairdone, out);
}

// Round 3
// 134.208 us; speedup vs baseline: 4.4989x; 2.1880x over previous
//
#include <hip/hip_runtime.h>

#define NPTS 8192
#define BN   16384          // B * N
#define D    32
#define R2   0.0009f        // float32(0.03**2)
#define SIMT 0.7f
#define RAD  0.03f
#define BLOCK 256
#define PBLOCK 1024         // pair kernel: 16 waves/block (proven 123us shape)
#define PWAVES 16
#define NGRP   (BN / 64)    // 256 i-groups, 1 block each
#define ZBINS 512
#define ZSCALE 1280.0f      // ZBINS / 0.4 (points lie in [0, 0.4))
#define AFIELDS 34          // nbc, cnt, acc[32]
#define CHUNK 160           // j-rows staged per LDS buffer

#define GLOBAL_AS __attribute__((address_space(1)))
#define LDS_AS    __attribute__((address_space(3)))

__device__ __forceinline__ void g2lds16(const void* g, void* l) {
  // dst = lds base (wave-uniform) + lane*16; src = per-lane global addr
  __builtin_amdgcn_global_load_lds((const GLOBAL_AS void*)g, (LDS_AS void*)l,
                                   16, 0, 0);
}
__device__ __forceinline__ void g2lds4(const void* g, void* l) {
  __builtin_amdgcn_global_load_lds((const GLOBAL_AS void*)g, (LDS_AS void*)l,
                                   4, 0, 0);
}

// ---------------------------------------------------------------------------
// histscan: z-histograms + inv-norms + leafcnt; LAST block (ticket) runs the
// 4 prefix-scans wave-parallel with shuffles. Cross-block visibility via
// agent-scope atomics (hist written by atomicAdd; read by atomic loads).
// ---------------------------------------------------------------------------
__global__ __launch_bounds__(BLOCK) void histscan_kernel(
    const float* __restrict__ pts, const float* __restrict__ emb,
    const int* __restrict__ leaf, float* __restrict__ invn,
    int* __restrict__ histA, int* __restrict__ histL,
    int* __restrict__ leafcnt, unsigned* __restrict__ done,
    int* __restrict__ rsA, int* __restrict__ rsL,
    int* __restrict__ curA, int* __restrict__ curL) {
  const int p = blockIdx.x * BLOCK + threadIdx.x;
  const float z = pts[3 * p + 2];
  int bin = (int)(z * ZSCALE); if (bin > ZBINS - 1) bin = ZBINS - 1;
  const int b = p >> 13;
  const int lf = leaf[p] > 0;
  atomicAdd(&histA[b * ZBINS + bin], 1);
  if (lf) atomicAdd(&histL[b * ZBINS + bin], 1);

  const float4* er = (const float4*)(emb + (size_t)p * D);
  float ss = 0.f;
#pragma unroll
  for (int i = 0; i < D / 4; ++i) {
    float4 v = er[i];
    ss += v.x * v.x + v.y * v.y + v.z * v.z + v.w * v.w;
  }
  invn[p] = 1.0f / fmaxf(sqrtf(ss), 1e-8f);

  const unsigned long long m = __ballot(lf);
  if ((threadIdx.x & 63) == 0) atomicAdd(&leafcnt[b], (int)__popcll(m));

  // ---- ticket: last finished block does the scans ----
  __shared__ int islast;
  __threadfence();
  if (threadIdx.x == 0) {
    const unsigned t = __hip_atomic_fetch_add(done, 1u, __ATOMIC_ACQ_REL,
                                              __HIP_MEMORY_SCOPE_AGENT);
    islast = (t == gridDim.x - 1);
  }
  __syncthreads();
  if (!islast) return;

  const int wv = threadIdx.x >> 6;      // wave 0..3: {A:b0, A:b1, L:b0, L:b1}
  const int lane = threadIdx.x & 63;
  const int sb = wv & 1;
  const int* __restrict__ h = (wv < 2) ? histA : histL;
  int* __restrict__ rs = (wv < 2) ? rsA : rsL;
  int* __restrict__ cu = (wv < 2) ? curA : curL;
  int carry = 0;
  for (int c = 0; c < ZBINS / 64; ++c) {
    const int idx = c * 64 + lane;
    const int v = __hip_atomic_load(&h[sb * ZBINS + idx], __ATOMIC_RELAXED,
                                    __HIP_MEMORY_SCOPE_AGENT);
    int incl = v;
#pragma unroll
    for (int off = 1; off < 64; off <<= 1) {
      const int t = __shfl_up(incl, off);
      if (lane >= off) incl += t;
    }
    const int excl = carry + incl - v;
    rs[sb * (ZBINS + 1) + idx] = excl;
    cu[sb * ZBINS + idx] = excl;
    carry += __shfl(incl, 63);
  }
  if (lane == 0) rs[sb * (ZBINS + 1) + ZBINS] = carry;
}

// ---------------------------------------------------------------------------
// scatter: counting-sort by z-bin. All points -> sortedA (+perm); leaf points
// -> compacted j-side arrays (pts4L with folded 0.5*(sq-R2), invL, embL).
// ---------------------------------------------------------------------------
__global__ __launch_bounds__(BLOCK) void scatter_kernel(
    const float* __restrict__ pts, const float* __restrict__ emb,
    const int* __restrict__ leaf, const float* __restrict__ invn,
    int* __restrict__ curA, int* __restrict__ curL,
    float4* __restrict__ sortedA, int* __restrict__ permA,
    float4* __restrict__ pts4L, float* __restrict__ invL,
    float* __restrict__ embL) {
  const int p = blockIdx.x * BLOCK + threadIdx.x;
  const float x = pts[3 * p + 0];
  const float y = pts[3 * p + 1];
  const float z = pts[3 * p + 2];
  const float sq = x * x + y * y + z * z;
  const int lf = leaf[p] > 0;
  const float inv = invn[p];
  int bin = (int)(z * ZSCALE); if (bin > ZBINS - 1) bin = ZBINS - 1;
  const int b = p >> 13;

  const int dst = b * NPTS + atomicAdd(&curA[b * ZBINS + bin], 1);
  sortedA[dst] = make_float4(x, y, z, lf ? inv : -inv);  // leaf in sign bit
  permA[dst] = p;

  if (lf) {
    const int dl = b * NPTS + atomicAdd(&curL[b * ZBINS + bin], 1);
    pts4L[dl] = make_float4(x, y, z, 0.5f * (sq - R2));
    invL[dl] = inv;
    const float4* __restrict__ s4 = (const float4*)(emb + (size_t)p * D);
    float4* __restrict__ d4 = (float4*)(embL + (size_t)dl * D);
#pragma unroll
    for (int k = 0; k < D / 4; ++k) d4[k] = s4[k];
  }
}

// ---------------------------------------------------------------------------
// pair + fused reduce/MLP. R11: R10 proved the per-hit embL path is the wall:
// wave-uniform j -> 8 s_load_dwordx4 per hit through the per-CU scalar cache,
// a shared shallow-miss-queue pipe. Doubling waves/CU (R10) made it WORSE
// (50->213us, VALUBusy 14->4.4%): the pipe saturates, TLP can't hide it.
// Fix: stage the group's j-window into LDS in CHUNK=160-row double-buffered
// slabs via async global_load_lds (coalesced, vmcnt-tracked), then per-hit
// reads are uniform-address ds_read_b128 broadcasts (conflict-free, 69 TB/s
// aggregate). Grid/epilogue revert to the proven 123us shape: 256 blocks x
// 16 waves, 1 block/CU, local LDS reduce + wave-0 MLP. LDS 57.3KB static.
// ---------------------------------------------------------------------------
__global__ __launch_bounds__(PBLOCK) void pair_kernel(
    const float4* __restrict__ sortedA, const int* __restrict__ permA,
    const float4* __restrict__ pts4L, const float* __restrict__ invL,
    const float* __restrict__ embL, const float* __restrict__ emb,
    const int* __restrict__ rsL, const int* __restrict__ leafcnt,
    const float* __restrict__ W1, const float* __restrict__ b1,
    const float* __restrict__ W2, const float* __restrict__ b2,
    float* __restrict__ out) {
  const int ig   = blockIdx.x;            // i-group of 64 (0..255)
  const int b    = ig >> 7;               // 128 i-groups per batch
  const int lane = threadIdx.x & 63;
  const int wv   = threadIdx.x >> 6;      // wave 0..15
  const int sg   = ig * 64 + lane;

  __shared__ __align__(16) float4 embS[2][CHUNK * 8];  // 40960 B
  __shared__ __align__(16) float4 ptsS[2][192];        //  6144 B (64-padded)
  __shared__ float invS[2][192];                       //  1536 B (64-padded)
  __shared__ float red[AFIELDS][64];                   //  8704 B
  for (int t = threadIdx.x; t < AFIELDS * 64; t += PBLOCK)
    (&red[0][0])[t] = 0.f;

  const float4 A = sortedA[sg];
  const float inv_i = fabsf(A.w);
  const float mhsq = -0.5f * (A.x * A.x + A.y * A.y + A.z * A.z);
  const int p = permA[sg];

  float4 ei[D / 4];                       // e_i; reused as passthrough in tail
  {
    const float4* __restrict__ e4 = (const float4*)(emb + (size_t)p * D);
#pragma unroll
    for (int k = 0; k < D / 4; ++k) ei[k] = e4[k];
  }

  float zmin = A.z, zmax = A.z;
#pragma unroll
  for (int off = 1; off < 64; off <<= 1) {
    zmin = fminf(zmin, __shfl_xor(zmin, off));
    zmax = fmaxf(zmax, __shfl_xor(zmax, off));
  }
  int klo = (int)((zmin - RAD) * ZSCALE) - 1; if (klo < 0) klo = 0;  // fp slack
  int khi = (int)((zmax + RAD) * ZSCALE) + 1; if (khi > ZBINS - 1) khi = ZBINS - 1;
  klo = __builtin_amdgcn_readfirstlane(klo);
  khi = __builtin_amdgcn_readfirstlane(khi);
  const int jlo = b * NPTS + rsL[b * (ZBINS + 1) + klo];
  const int jhi = b * NPTS + rsL[b * (ZBINS + 1) + khi + 1];
  const int len = jhi - jlo;              // block-uniform (same 64 i's per wave)

  float acc[D];
#pragma unroll
  for (int d = 0; d < D; ++d) acc[d] = 0.f;
  float nbc = 0.f, cnt = 0.f;

  // ---- async stage of one chunk (all waves; wave-uniform lds bases) ----
  auto stage = [&](int buf, int base, int L) {
    const int nf4 = L * 8;                // embS float4 count (<= CHUNK*8)
    for (int t0 = wv * 64; t0 < nf4; t0 += PWAVES * 64)
      g2lds16((const char*)embL + (((size_t)base * 8 + t0 + lane) << 4),
              &embS[buf][t0]);
    for (int t0 = wv * 64; t0 < L; t0 += PWAVES * 64)   // waves 0..2
      g2lds16((const char*)pts4L + (((size_t)base + t0 + lane) << 4),
              &ptsS[buf][t0]);
    {
      const int t0 = (wv - 4) * 64;       // waves 4..6 stage invL
      if (t0 >= 0 && t0 < L)
        g2lds4((const char*)invL + (((size_t)base + t0 + lane) << 2),
               &invS[buf][t0]);
    }
  };

  // ---- process this wave's 1/16 slice of the staged chunk ----
  auto process = [&](int buf, int L) {
    const int s0 = (L * wv) / PWAVES;
    const int s1 = (L * (wv + 1)) / PWAVES;
    if (s0 >= s1) return;
    float4 c = ptsS[buf][s0];
    for (int jl = s0; jl < s1; ++jl) {
      const float4 cn = ptsS[buf][(jl + 1 < s1) ? (jl + 1) : s0];
      const float t = fmaf(A.z, c.z, fmaf(A.y, c.y, fmaf(A.x, c.x, mhsq)));
      if (t > c.w) {                      // d2 < R2; j is leaf by construction
        nbc += 1.0f;
        const float4* __restrict__ ej4 = &embS[buf][jl * 8];
        float s0_ = 0.f, s1_ = 0.f, s2_ = 0.f, s3_ = 0.f;
#pragma unroll
        for (int k = 0; k < D / 4; ++k) {
          const float4 vj = ej4[k];       // uniform addr -> LDS broadcast
          s0_ = fmaf(ei[k].x, vj.x, s0_);
          s1_ = fmaf(ei[k].y, vj.y, s1_);
          s2_ = fmaf(ei[k].z, vj.z, s2_);
          s3_ = fmaf(ei[k].w, vj.w, s3_);
        }
        const float sm = ((s0_ + s1_) + (s2_ + s3_)) * inv_i * invS[buf][jl];
        if (sm > SIMT) {
          cnt += 1.0f;
#pragma unroll
          for (int k = 0; k < D / 4; ++k) {
            const float4 vj = ej4[k];
            acc[4 * k + 0] += vj.x;
            acc[4 * k + 1] += vj.y;
            acc[4 * k + 2] += vj.z;
            acc[4 * k + 3] += vj.w;
          }
        }
      }
      c = cn;
    }
  };

  const int nch = (len + CHUNK - 1) / CHUNK;
  if (nch > 0) {
    stage(0, jlo, (len < CHUNK) ? len : CHUNK);
    __syncthreads();                      // drains vmcnt -> chunk 0 ready
    for (int k = 0; k < nch; ++k) {
      const int cur = k & 1;
      if (k + 1 < nch) {
        const int base = jlo + (k + 1) * CHUNK;
        const int L = (jhi - base < CHUNK) ? (jhi - base) : CHUNK;
        stage(cur ^ 1, base, L);          // async; overlaps with process
      }
      const int Lc = (len - k * CHUNK < CHUNK) ? (len - k * CHUNK) : CHUNK;
      process(cur, Lc);
      __syncthreads();                    // staged data ready + cur free
    }
  } else {
    __syncthreads();                      // match red[] init barrier semantics
  }

  // combine the block's 16 waves in LDS (sparse ds-atomics)
  if (nbc != 0.f) atomicAdd(&red[0][lane], nbc);
  if (cnt != 0.f) {
    atomicAdd(&red[1][lane], cnt);
#pragma unroll
    for (int d = 0; d < D; ++d) atomicAdd(&red[2 + d][lane], acc[d]);
  }
  __syncthreads();

  // ---- fused epilogue: wave 0, one lane per point ----
  if (threadIdx.x < 64) {
    const float tnbc = red[0][lane];
    const float tcnt = red[1][lane];
    const float rinv = 1.0f / fmaxf(tcnt, 1.0f);

    float e[D];
#pragma unroll
    for (int k = 0; k < D / 4; ++k) {
      e[4 * k + 0] = ei[k].x; e[4 * k + 1] = ei[k].y;
      e[4 * k + 2] = ei[k].z; e[4 * k + 3] = ei[k].w;
    }

    float h[D];
#pragma unroll
    for (int k = 0; k < D; ++k) h[k] = b1[k];
    for (int d = 0; d < D; ++d) {
      const float c = e[d];
      const float* __restrict__ w = W1 + (size_t)d * D;
#pragma unroll
      for (int k = 0; k < D; ++k) h[k] = fmaf(c, w[k], h[k]);
    }
    for (int d = 0; d < D; ++d) {
      const float c = red[2 + d][lane] * rinv;   // mean_sim[d]
      const float* __restrict__ w = W1 + (size_t)(D + d) * D;
#pragma unroll
      for (int k = 0; k < D; ++k) h[k] = fmaf(c, w[k], h[k]);
    }
#pragma unroll
    for (int k = 0; k < D; ++k) h[k] = fmaxf(h[k], 0.f);

    float o[D];
#pragma unroll
    for (int m = 0; m < D; ++m) o[m] = b2[m];
    for (int k = 0; k < D; ++k) {
      const float c = h[k];
      const float* __restrict__ w = W2 + (size_t)k * D;
#pragma unroll
      for (int m = 0; m < D; ++m) o[m] = fmaf(c, w[m], o[m]);
    }

    const bool lf = A.w > 0.f;
    const bool cond = lf && (tnbc >= 2.0f) && (tcnt >= 1.0f) && (leafcnt[b] >= 10);

    float4* outr = (float4*)(out + (size_t)p * D);
#pragma unroll
    for (int i = 0; i < D / 4; ++i) {
      float4 v;
      if (cond) { v.x = o[4*i+0]; v.y = o[4*i+1]; v.z = o[4*i+2]; v.w = o[4*i+3]; }
      else      { v = ei[i]; }
      outr[i] = v;
    }
  }
}

// ---------------------------------------------------------------------------
extern "C" void kernel_launch(void* const* d_in, const int* in_sizes, int n_in,
                              void* d_out, int out_size, void* d_ws, size_t ws_size,
                              hipStream_t stream) {
  (void)in_sizes; (void)n_in; (void)out_size; (void)ws_size;
  const float* pts  = (const float*)d_in[0];
  const float* emb  = (const float*)d_in[1];
  const int*   leaf = (const int*)d_in[2];
  const float* W1   = (const float*)d_in[3];
  const float* b1   = (const float*)d_in[4];
  const float* W2   = (const float*)d_in[5];
  const float* b2   = (const float*)d_in[6];
  float* out = (float*)d_out;

  char* ws = (char*)d_ws;
  size_t off = 0;
  auto alloc = [&](size_t bytes) { void* r = ws + off; off = (off + bytes + 15) & ~(size_t)15; return r; };

  // +CHUNK rows of slack on j-side arrays: staging rounds up to 64-lane
  // granularity and may read past jhi; slack keeps those reads in-bounds.
  float4*   sortedA = (float4*)alloc((size_t)BN * 16);
  int*      permA   = (int*)alloc((size_t)BN * 4);
  float4*   pts4L   = (float4*)alloc((size_t)(BN + CHUNK) * 16);
  float*    invL    = (float*)alloc((size_t)(BN + CHUNK) * 4);
  float*    embL    = (float*)alloc((size_t)(BN + CHUNK) * D * 4);
  float*    invn    = (float*)alloc((size_t)BN * 4);
  int*      rsA     = (int*)alloc(2 * (ZBINS + 1) * 4);
  int*      rsL     = (int*)alloc(2 * (ZBINS + 1) * 4);
  int*      curA    = (int*)alloc(2 * ZBINS * 4);
  int*      curL    = (int*)alloc(2 * ZBINS * 4);
  int*      histA   = (int*)alloc(2 * ZBINS * 4);   // histA..done contiguous
  int*      histL   = (int*)alloc(2 * ZBINS * 4);   //   -> single 8.2 KB memset
  int*      leafcnt = (int*)alloc(16);
  unsigned* done    = (unsigned*)alloc(16);

  hipMemsetAsync(histA, 0, 2 * (2 * ZBINS * 4) + 32, stream);
  histscan_kernel<<<BN / BLOCK, BLOCK, 0, stream>>>(
      pts, emb, leaf, invn, histA, histL, leafcnt, done, rsA, rsL, curA, curL);
  scatter_kernel<<<BN / BLOCK, BLOCK, 0, stream>>>(
      pts, emb, leaf, invn, curA, curL, sortedA, permA, pts4L, invL, embL);
  pair_kernel<<<NGRP, PBLOCK, 0, stream>>>(
      sortedA, permA, pts4L, invL, embL, emb, rsL, leafcnt,
      W1, b1, W2, b2, out);
}

// Round 4
// 115.057 us; speedup vs baseline: 5.2477x; 1.1664x over previous
//
#include <hip/hip_runtime.h>

#define NPTS 8192
#define BN   16384          // B * N
#define D    32
#define R2   0.0009f        // float32(0.03**2)
#define SIMT 0.7f
#define RAD  0.03f
#define BLOCK 256
#define PBLOCK 1024         // pair kernel: 16 waves/block (proven shape)
#define PWAVES 16
#define NGRP   (BN / 64)    // 256 i-groups, 1 block each
#define ZBINS 512
#define ZSCALE 1280.0f      // ZBINS / 0.4 (points lie in [0, 0.4))
#define AFIELDS 34          // nbc, cnt, acc[32]
#define CHUNK 512           // j-rows staged per LDS buffer (pts only now)

#define GLOBAL_AS __attribute__((address_space(1)))
#define LDS_AS    __attribute__((address_space(3)))

__device__ __forceinline__ void g2lds16(const void* g, void* l) {
  // dst = lds base (wave-uniform) + lane*16; src = per-lane global addr
  __builtin_amdgcn_global_load_lds((const GLOBAL_AS void*)g, (LDS_AS void*)l,
                                   16, 0, 0);
}

// ---------------------------------------------------------------------------
// histscan: z-histograms + inv-norms + leafcnt; LAST block (ticket) runs the
// 4 prefix-scans wave-parallel with shuffles. Cross-block visibility via
// agent-scope atomics (hist written by atomicAdd; read by atomic loads).
// ---------------------------------------------------------------------------
__global__ __launch_bounds__(BLOCK) void histscan_kernel(
    const float* __restrict__ pts, const float* __restrict__ emb,
    const int* __restrict__ leaf, float* __restrict__ invn,
    int* __restrict__ histA, int* __restrict__ histL,
    int* __restrict__ leafcnt, unsigned* __restrict__ done,
    int* __restrict__ rsA, int* __restrict__ rsL,
    int* __restrict__ curA, int* __restrict__ curL) {
  const int p = blockIdx.x * BLOCK + threadIdx.x;
  const float z = pts[3 * p + 2];
  int bin = (int)(z * ZSCALE); if (bin > ZBINS - 1) bin = ZBINS - 1;
  const int b = p >> 13;
  const int lf = leaf[p] > 0;
  atomicAdd(&histA[b * ZBINS + bin], 1);
  if (lf) atomicAdd(&histL[b * ZBINS + bin], 1);

  const float4* er = (const float4*)(emb + (size_t)p * D);
  float ss = 0.f;
#pragma unroll
  for (int i = 0; i < D / 4; ++i) {
    float4 v = er[i];
    ss += v.x * v.x + v.y * v.y + v.z * v.z + v.w * v.w;
  }
  invn[p] = 1.0f / fmaxf(sqrtf(ss), 1e-8f);

  const unsigned long long m = __ballot(lf);
  if ((threadIdx.x & 63) == 0) atomicAdd(&leafcnt[b], (int)__popcll(m));

  // ---- ticket: last finished block does the scans ----
  __shared__ int islast;
  __threadfence();
  if (threadIdx.x == 0) {
    const unsigned t = __hip_atomic_fetch_add(done, 1u, __ATOMIC_ACQ_REL,
                                              __HIP_MEMORY_SCOPE_AGENT);
    islast = (t == gridDim.x - 1);
  }
  __syncthreads();
  if (!islast) return;

  const int wv = threadIdx.x >> 6;      // wave 0..3: {A:b0, A:b1, L:b0, L:b1}
  const int lane = threadIdx.x & 63;
  const int sb = wv & 1;
  const int* __restrict__ h = (wv < 2) ? histA : histL;
  int* __restrict__ rs = (wv < 2) ? rsA : rsL;
  int* __restrict__ cu = (wv < 2) ? curA : curL;
  int carry = 0;
  for (int c = 0; c < ZBINS / 64; ++c) {
    const int idx = c * 64 + lane;
    const int v = __hip_atomic_load(&h[sb * ZBINS + idx], __ATOMIC_RELAXED,
                                    __HIP_MEMORY_SCOPE_AGENT);
    int incl = v;
#pragma unroll
    for (int off = 1; off < 64; off <<= 1) {
      const int t = __shfl_up(incl, off);
      if (lane >= off) incl += t;
    }
    const int excl = carry + incl - v;
    rs[sb * (ZBINS + 1) + idx] = excl;
    cu[sb * ZBINS + idx] = excl;
    carry += __shfl(incl, 63);
  }
  if (lane == 0) rs[sb * (ZBINS + 1) + ZBINS] = carry;
}

// ---------------------------------------------------------------------------
// scatter: counting-sort by z-bin. All points -> sortedA (+perm); leaf points
// -> compacted j-side arrays (pts4L with folded 0.5*(sq-R2), invL, embL).
// ---------------------------------------------------------------------------
__global__ __launch_bounds__(BLOCK) void scatter_kernel(
    const float* __restrict__ pts, const float* __restrict__ emb,
    const int* __restrict__ leaf, const float* __restrict__ invn,
    int* __restrict__ curA, int* __restrict__ curL,
    float4* __restrict__ sortedA, int* __restrict__ permA,
    float4* __restrict__ pts4L, float* __restrict__ invL,
    float* __restrict__ embL) {
  const int p = blockIdx.x * BLOCK + threadIdx.x;
  const float x = pts[3 * p + 0];
  const float y = pts[3 * p + 1];
  const float z = pts[3 * p + 2];
  const float sq = x * x + y * y + z * z;
  const int lf = leaf[p] > 0;
  const float inv = invn[p];
  int bin = (int)(z * ZSCALE); if (bin > ZBINS - 1) bin = ZBINS - 1;
  const int b = p >> 13;

  const int dst = b * NPTS + atomicAdd(&curA[b * ZBINS + bin], 1);
  sortedA[dst] = make_float4(x, y, z, lf ? inv : -inv);  // leaf in sign bit
  permA[dst] = p;

  if (lf) {
    const int dl = b * NPTS + atomicAdd(&curL[b * ZBINS + bin], 1);
    pts4L[dl] = make_float4(x, y, z, 0.5f * (sq - R2));
    invL[dl] = inv;
    const float4* __restrict__ s4 = (const float4*)(emb + (size_t)p * D);
    float4* __restrict__ d4 = (float4*)(embL + (size_t)dl * D);
#pragma unroll
    for (int k = 0; k < D / 4; ++k) d4[k] = s4[k];
  }
}

// ---------------------------------------------------------------------------
// pair + fused reduce/MLP. R12: R11's LDS staging matched baseline (48.5us)
// because the structure wastes the per-CU LDS pipe: ~460 hit-rows/block each
// broadcast-read 8x ds_read_b128 of the SAME address (16B useful of 1KB/slot)
// with ~1 of 64 lanes active in the dot (~2% lane util). 44K cyc of LDS pipe
// per CU = the ~18us floor, plus a 1.8x straggler spread (Occupancy 27% vs
// 50% for full-lifetime blocks). Fix: split phases. (1) geometric pass:
// distance-test rows (3 fma), ballot hits, append packed (j<<6)|lane to a
// per-wave LDS queue (qtail from popc, no atomics). Only pts4L is staged
// (16B/row; embS + its 8x fetch and 41MB write-side traffic are gone).
// (2) drain at 64 entries: one (i,j) pair per lane -> per-lane DISTINCT
// addresses at full bandwidth: ei from XOR-swizzled eiS (k^(il&7); unswizzled
// 128B stride = same-bank 16-way conflict), ej straight from L2-resident
// embL. Rare sim>SIMT (self-pairs mostly) -> sparse ds-atomics into red.
// Frees acc[32]+ei regs; epilogue re-reads e_i from eiS.
// ---------------------------------------------------------------------------
__global__ __launch_bounds__(PBLOCK) void pair_kernel(
    const float4* __restrict__ sortedA, const int* __restrict__ permA,
    const float4* __restrict__ pts4L, const float* __restrict__ invL,
    const float* __restrict__ embL, const float* __restrict__ emb,
    const int* __restrict__ rsL, const int* __restrict__ leafcnt,
    const float* __restrict__ W1, const float* __restrict__ b1,
    const float* __restrict__ W2, const float* __restrict__ b2,
    float* __restrict__ out) {
  const int ig   = blockIdx.x;            // i-group of 64 (0..255)
  const int b    = ig >> 7;               // 128 i-groups per batch
  const int lane = threadIdx.x & 63;
  const int wv   = threadIdx.x >> 6;      // wave 0..15
  const int sg   = ig * 64 + lane;

  __shared__ __align__(16) float4 ptsS[2][CHUNK];   // 16 KB
  __shared__ __align__(16) float4 eiS4[64 * 8];     //  8 KB, XOR-swizzled
  __shared__ float invIS[64];
  __shared__ int   queueS[PWAVES][128];             //  8 KB ring/wave
  __shared__ float red[AFIELDS][64];                //  8.7 KB
  for (int t = threadIdx.x; t < AFIELDS * 64; t += PBLOCK)
    (&red[0][0])[t] = 0.f;

  const float4 A = sortedA[sg];
  const float inv_i = fabsf(A.w);
  const float mhsq = -0.5f * (A.x * A.x + A.y * A.y + A.z * A.z);
  const int p = permA[sg];

  if (wv == 0) {                          // block-shared e_i copy (swizzled)
    const float4* __restrict__ e4 = (const float4*)(emb + (size_t)p * D);
#pragma unroll
    for (int k = 0; k < D / 4; ++k) eiS4[lane * 8 + (k ^ (lane & 7))] = e4[k];
    invIS[lane] = inv_i;
  }

  float zmin = A.z, zmax = A.z;
#pragma unroll
  for (int off = 1; off < 64; off <<= 1) {
    zmin = fminf(zmin, __shfl_xor(zmin, off));
    zmax = fmaxf(zmax, __shfl_xor(zmax, off));
  }
  int klo = (int)((zmin - RAD) * ZSCALE) - 1; if (klo < 0) klo = 0;  // fp slack
  int khi = (int)((zmax + RAD) * ZSCALE) + 1; if (khi > ZBINS - 1) khi = ZBINS - 1;
  klo = __builtin_amdgcn_readfirstlane(klo);
  khi = __builtin_amdgcn_readfirstlane(khi);
  const int jlo = b * NPTS + rsL[b * (ZBINS + 1) + klo];
  const int jhi = b * NPTS + rsL[b * (ZBINS + 1) + khi + 1];
  const int len = jhi - jlo;              // block-uniform

  float nbc = 0.f;
  int qtail = 0, qdone = 0;

  const float4* __restrict__ embQ = (const float4*)embL;

  // ---- drain n (<=64) queued pairs: one pair per lane, dense ----
  auto drain = [&](int n) {
    if (lane < n) {
      const int e  = queueS[wv][(qdone + lane) & 127];
      const int il = e & 63;
      const int j  = e >> 6;
      float4 bv[D / 4];
#pragma unroll
      for (int k = 0; k < D / 4; ++k) bv[k] = embQ[(size_t)j * 8 + k];
      const float invj = invL[j];
      float s0 = 0.f, s1 = 0.f, s2 = 0.f, s3 = 0.f;
#pragma unroll
      for (int k = 0; k < D / 4; ++k) {
        const float4 av = eiS4[il * 8 + (k ^ (il & 7))];
        s0 = fmaf(av.x, bv[k].x, s0);
        s1 = fmaf(av.y, bv[k].y, s1);
        s2 = fmaf(av.z, bv[k].z, s2);
        s3 = fmaf(av.w, bv[k].w, s3);
      }
      const float sim = ((s0 + s1) + (s2 + s3)) * invIS[il] * invj;
      if (sim > SIMT) {                   // rare (mostly self-pairs)
        atomicAdd(&red[1][il], 1.0f);
#pragma unroll
        for (int k = 0; k < D / 4; ++k) {
          atomicAdd(&red[2 + 4 * k + 0][il], bv[k].x);
          atomicAdd(&red[2 + 4 * k + 1][il], bv[k].y);
          atomicAdd(&red[2 + 4 * k + 2][il], bv[k].z);
          atomicAdd(&red[2 + 4 * k + 3][il], bv[k].w);
        }
      }
    }
    qdone += n;
  };

  // ---- async stage of one pts chunk (waves 0..7, 1 instr each) ----
  auto stage = [&](int buf, int base, int L) {
    for (int t0 = wv * 64; t0 < L; t0 += PWAVES * 64)
      g2lds16((const char*)pts4L + (((size_t)(base + t0 + lane)) << 4),
              &ptsS[buf][t0]);
  };

  // ---- geometric pass over this wave's slice of the staged chunk ----
  auto process = [&](int buf, int jbase, int L) {
    const int s0 = (L * wv) / PWAVES;
    const int s1 = (L * (wv + 1)) / PWAVES;
    if (s0 >= s1) return;
    float4 c = ptsS[buf][s0];
    for (int jl = s0; jl < s1; ++jl) {
      const float4 cn = ptsS[buf][(jl + 1 < s1) ? (jl + 1) : s0];
      const float t = fmaf(A.z, c.z, fmaf(A.y, c.y, fmaf(A.x, c.x, mhsq)));
      const bool hit = t > c.w;           // d2 < R2; j is leaf by construction
      const unsigned long long m = __ballot(hit);
      if (m) {
        if (hit) {
          nbc += 1.0f;
          const int below = __popcll(m & ((1ull << lane) - 1ull));
          queueS[wv][(qtail + below) & 127] = ((jbase + jl) << 6) | lane;
        }
        qtail += (int)__popcll(m);        // uniform, no atomics
        if (qtail - qdone >= 64) drain(64);
      }
      c = cn;
    }
  };

  const int nch = (len + CHUNK - 1) / CHUNK;
  if (nch > 0) stage(0, jlo, (len < CHUNK) ? len : CHUNK);
  __syncthreads();                        // red/eiS init + chunk 0 ready
  for (int k = 0; k < nch; ++k) {
    const int cur = k & 1;
    if (k + 1 < nch) {
      const int base = jlo + (k + 1) * CHUNK;
      const int L = (jhi - base < CHUNK) ? (jhi - base) : CHUNK;
      stage(cur ^ 1, base, L);            // async; overlaps with process
    }
    const int base = jlo + k * CHUNK;
    const int Lc = (jhi - base < CHUNK) ? (jhi - base) : CHUNK;
    process(cur, base, Lc);
    __syncthreads();                      // staged data ready + cur free
  }
  drain(qtail - qdone);                   // final flush (<64, queue is global-indexed)

  if (nbc != 0.f) atomicAdd(&red[0][lane], nbc);
  __syncthreads();

  // ---- fused epilogue: wave 0, one lane per point ----
  if (threadIdx.x < 64) {
    const float tnbc = red[0][lane];
    const float tcnt = red[1][lane];
    const float rinv = 1.0f / fmaxf(tcnt, 1.0f);

    float e[D];
#pragma unroll
    for (int k = 0; k < D / 4; ++k) {
      const float4 v = eiS4[lane * 8 + (k ^ (lane & 7))];
      e[4 * k + 0] = v.x; e[4 * k + 1] = v.y;
      e[4 * k + 2] = v.z; e[4 * k + 3] = v.w;
    }

    float h[D];
#pragma unroll
    for (int k = 0; k < D; ++k) h[k] = b1[k];
    for (int d = 0; d < D; ++d) {
      const float c = e[d];
      const float* __restrict__ w = W1 + (size_t)d * D;
#pragma unroll
      for (int k = 0; k < D; ++k) h[k] = fmaf(c, w[k], h[k]);
    }
    for (int d = 0; d < D; ++d) {
      const float c = red[2 + d][lane] * rinv;   // mean_sim[d]
      const float* __restrict__ w = W1 + (size_t)(D + d) * D;
#pragma unroll
      for (int k = 0; k < D; ++k) h[k] = fmaf(c, w[k], h[k]);
    }
#pragma unroll
    for (int k = 0; k < D; ++k) h[k] = fmaxf(h[k], 0.f);

    float o[D];
#pragma unroll
    for (int m = 0; m < D; ++m) o[m] = b2[m];
    for (int k = 0; k < D; ++k) {
      const float c = h[k];
      const float* __restrict__ w = W2 + (size_t)k * D;
#pragma unroll
      for (int m = 0; m < D; ++m) o[m] = fmaf(c, w[m], o[m]);
    }

    const bool lf = A.w > 0.f;
    const bool cond = lf && (tnbc >= 2.0f) && (tcnt >= 1.0f) && (leafcnt[b] >= 10);

    float4* outr = (float4*)(out + (size_t)p * D);
#pragma unroll
    for (int i = 0; i < D / 4; ++i) {
      float4 v;
      if (cond) { v.x = o[4*i+0]; v.y = o[4*i+1]; v.z = o[4*i+2]; v.w = o[4*i+3]; }
      else      { v.x = e[4*i+0]; v.y = e[4*i+1]; v.z = e[4*i+2]; v.w = e[4*i+3]; }
      outr[i] = v;
    }
  }
}

// ---------------------------------------------------------------------------
extern "C" void kernel_launch(void* const* d_in, const int* in_sizes, int n_in,
                              void* d_out, int out_size, void* d_ws, size_t ws_size,
                              hipStream_t stream) {
  (void)in_sizes; (void)n_in; (void)out_size; (void)ws_size;
  const float* pts  = (const float*)d_in[0];
  const float* emb  = (const float*)d_in[1];
  const int*   leaf = (const int*)d_in[2];
  const float* W1   = (const float*)d_in[3];
  const float* b1   = (const float*)d_in[4];
  const float* W2   = (const float*)d_in[5];
  const float* b2   = (const float*)d_in[6];
  float* out = (float*)d_out;

  char* ws = (char*)d_ws;
  size_t off = 0;
  auto alloc = [&](size_t bytes) { void* r = ws + off; off = (off + bytes + 15) & ~(size_t)15; return r; };

  // +CHUNK rows of slack on j-side arrays: staging rounds up to 64-lane
  // granularity and may read past jhi; slack keeps those reads in-bounds.
  float4*   sortedA = (float4*)alloc((size_t)BN * 16);
  int*      permA   = (int*)alloc((size_t)BN * 4);
  float4*   pts4L   = (float4*)alloc((size_t)(BN + CHUNK) * 16);
  float*    invL    = (float*)alloc((size_t)(BN + CHUNK) * 4);
  float*    embL    = (float*)alloc((size_t)(BN + CHUNK) * D * 4);
  float*    invn    = (float*)alloc((size_t)BN * 4);
  int*      rsA     = (int*)alloc(2 * (ZBINS + 1) * 4);
  int*      rsL     = (int*)alloc(2 * (ZBINS + 1) * 4);
  int*      curA    = (int*)alloc(2 * ZBINS * 4);
  int*      curL    = (int*)alloc(2 * ZBINS * 4);
  int*      histA   = (int*)alloc(2 * ZBINS * 4);   // histA..done contiguous
  int*      histL   = (int*)alloc(2 * ZBINS * 4);   //   -> single 8.2 KB memset
  int*      leafcnt = (int*)alloc(16);
  unsigned* done    = (unsigned*)alloc(16);

  hipMemsetAsync(histA, 0, 2 * (2 * ZBINS * 4) + 32, stream);
  histscan_kernel<<<BN / BLOCK, BLOCK, 0, stream>>>(
      pts, emb, leaf, invn, histA, histL, leafcnt, done, rsA, rsL, curA, curL);
  scatter_kernel<<<BN / BLOCK, BLOCK, 0, stream>>>(
      pts, emb, leaf, invn, curA, curL, sortedA, permA, pts4L, invL, embL);
  pair_kernel<<<NGRP, PBLOCK, 0, stream>>>(
      sortedA, permA, pts4L, invL, embL, emb, rsL, leafcnt,
      W1, b1, W2, b2, out);
}